// Round 5
// baseline (1223.286 us; speedup 1.0000x reference)
//
#include <hip/hip_runtime.h>
#include <stdint.h>

#define NB 8
#define NPTS 4096
#define NS 1024
#define NK 32
#define PC 64        // point feature channels
#define NROWS (NB*NS*NK)   // 262144
#define R2 0.04f

typedef __attribute__((ext_vector_type(8))) short bf16x8;   // 8 bf16 in 4 VGPRs
typedef __attribute__((ext_vector_type(4))) float f32x4;    // MFMA 16x16 accumulator

__device__ __forceinline__ float bf2f(uint16_t u){
    uint32_t v = ((uint32_t)u) << 16;
    return __uint_as_float(v);
}
__device__ __forceinline__ uint16_t f2bf(float f){
    uint32_t u = __float_as_uint(f);
    uint32_t r = (u + 0x7FFFu + ((u >> 16) & 1u)) >> 16;
    return (uint16_t)r;
}
__device__ __forceinline__ bf16x8 load_bf8(const uint16_t* p){
    return *reinterpret_cast<const bf16x8*>(p);
}

// float max with DPP-moved partner (VALU pipe). bound_ctrl=true fills 0.0f,
// which never wins: distances are > 0 (selected points go to 0 but never all).
#define DPPMAXF(v, ctrl, rmask)                                                \
    {                                                                          \
        float _o = __uint_as_float((uint32_t)__builtin_amdgcn_update_dpp(      \
            0, (int)__float_as_uint(v), (ctrl), (rmask), 0xf, true));          \
        v = fmaxf(v, _o);                                                      \
    }

// ---------------------------------------------------------------- FPS
// one block (256 thr) per batch; 16 points/thread (blocked). Float-only DPP
// wave max + ballot owner-find; winner's COORDS travel through the cand slot
// (no dependent LX[cur] read; `cur` index never materializes).
// DO NOT TOUCH the distance math: plain mul+add with contract(off) is
// bit-exact vs reference (verified rounds 2-4). Tiebreak = smallest global
// index == first ballot lane + smallest j (blocked layout keeps order).
#define FT 16
__global__ __launch_bounds__(256) void fps_kernel(const float* __restrict__ xyz,
                                                  float* __restrict__ out_newxyz){
    __shared__ float4 LP[NPTS];          // (x,y,z,pad)
    __shared__ float4 candf[2][4];       // (wavemax, x, y, z)
    const int b = blockIdx.x, t = threadIdx.x;
    const float* base = xyz + (size_t)b * (NPTS*3);
    float px[FT], py[FT], pz[FT], pd[FT];
#pragma unroll
    for (int j = 0; j < FT; ++j){
        int i = t*FT + j;
        float x = base[i*3+0], y = base[i*3+1], z = base[i*3+2];
        px[j]=x; py[j]=y; pz[j]=z; pd[j]=1e10f;
        LP[i] = make_float4(x, y, z, 0.f);
    }
    float cx = base[0], cy = base[1], cz = base[2];   // first centroid = point 0
    __syncthreads();
    const int wave = t >> 6, lane = t & 63;
    for (int s = 0; s < NS; ++s){
        if (t == 0){
            float* o = out_newxyz + ((size_t)b*NS + s)*3;
            o[0]=cx; o[1]=cy; o[2]=cz;
        }
        float lmax = -1.0f;
#pragma unroll
        for (int j = 0; j < FT; ++j){
            float d;
            {
#pragma clang fp contract(off)
                float dx = px[j]-cx, dy = py[j]-cy, dz = pz[j]-cz;
                d = ((dx*dx) + (dy*dy)) + (dz*dz);
            }
            float nd = fminf(pd[j], d);
            pd[j] = nd;
            lmax = fmaxf(lmax, nd);
        }
        // wave64 float max -> lane 63
        float m = lmax;
        DPPMAXF(m, 0x111, 0xf);   // row_shr:1
        DPPMAXF(m, 0x112, 0xf);   // row_shr:2
        DPPMAXF(m, 0x114, 0xf);   // row_shr:4
        DPPMAXF(m, 0x118, 0xf);   // row_shr:8
        DPPMAXF(m, 0x142, 0xa);   // row_bcast:15 -> rows 1,3
        DPPMAXF(m, 0x143, 0xc);   // row_bcast:31 -> rows 2,3
        float wm = __uint_as_float((uint32_t)__builtin_amdgcn_readlane(
            (int)__float_as_uint(m), 63));
        // owner = first lane holding the max (lowest lane = lowest indices)
        unsigned long long bal = __ballot(lmax == wm);
        int owner = __ffsll(bal) - 1;
        int p = s & 1;
        if (lane == owner){
            int jw = 64;
#pragma unroll
            for (int j = FT-1; j >= 0; --j) jw = (pd[j] == wm) ? j : jw;  // smallest j
            float4 c = LP[t*FT + jw];
            candf[p][wave] = make_float4(wm, c.x, c.y, c.z);
        }
        __syncthreads();
        float4 s0 = candf[p][0], s1 = candf[p][1];
        float4 s2 = candf[p][2], s3 = candf[p][3];
        // strictly-greater: earlier wave wins exact-value ties (lower indices)
        float4 w01 = (s1.x > s0.x) ? s1 : s0;
        float4 w23 = (s3.x > s2.x) ? s3 : s2;
        float4 wv  = (w23.x > w01.x) ? w23 : w01;
        cx = wv.y; cy = wv.z; cz = wv.w;
    }
}

// ---------------------------------------------------------------- query ball
// UNCHANGED (verified).
__global__ __launch_bounds__(256) void qball_kernel(const float* __restrict__ xyz,
                                                    const float* __restrict__ newxyz,
                                                    int* __restrict__ idx_out){
    int gid = blockIdx.x*256 + threadIdx.x;
    int w = gid >> 6, lane = gid & 63;
    int b = w >> 10;
    const float* q = newxyz + (size_t)w*3;
    float qx = q[0], qy = q[1], qz = q[2];
    float qn = qx*qx;
    qn = fmaf(qy, qy, qn);
    qn = fmaf(qz, qz, qn);
    const float* base = xyz + (size_t)b * (NPTS*3);
    int cnt = 0, first = 0;
    for (int c0 = 0; c0 < NPTS; c0 += 64){
        int i = c0 + lane;
        float x = base[i*3+0], y = base[i*3+1], z = base[i*3+2];
        float xn = x*x;
        xn = fmaf(y, y, xn);
        xn = fmaf(z, z, xn);
        float dot = qx*x;
        dot = fmaf(qy, y, dot);
        dot = fmaf(qz, z, dot);
        float d;
        {
#pragma clang fp contract(off)
            d = -2.0f * dot;
            d = d + qn;
            d = d + xn;
        }
        bool in = !(d > R2);
        unsigned long long m = __ballot(in);
        if (in){
            int rank = __popcll(m & ((1ull << lane) - 1ull));
            int pos = cnt + rank;
            if (pos < NK) idx_out[(size_t)w*NK + pos] = i;
        }
        if (cnt == 0 && m) first = c0 + (__ffsll((unsigned long long)m) - 1);
        cnt += __popcll(m);
        if (cnt >= NK) break;
    }
    if (cnt < NK){
        for (int p = cnt + lane; p < NK; p += 64) idx_out[(size_t)w*NK + p] = first;
    }
}

// ---------------------------------------------------------------- weight prep (fp32 -> bf16)
// MFMA B-operand wants [out][in] k-contiguous = ORIGINAL layout. w0 padded 67->96.
__global__ void prep_kernel(const float* __restrict__ w0, const float* __restrict__ w1,
                            const float* __restrict__ w2, uint16_t* __restrict__ w0b,
                            uint16_t* __restrict__ w1b, uint16_t* __restrict__ w2b){
    int t = blockIdx.x*256 + threadIdx.x;
    int stride = gridDim.x*256;
    for (int i = t; i < 64*96; i += stride){
        int n = i/96, c = i%96;
        w0b[i] = (c < 67) ? f2bf(w0[n*67 + c]) : (uint16_t)0;
    }
    for (int i = t; i < 64*64; i += stride)  w1b[i] = f2bf(w1[i]);
    for (int i = t; i < 128*64; i += stride) w2b[i] = f2bf(w2[i]);
}

// ---------------------------------------------------------------- layer 0: gather + GEMM 262144 x 96 -> 64 (MFMA)
__global__ __launch_bounds__(256) void layer0_mfma(const float* __restrict__ xyz,
                                                   const float* __restrict__ pts,
                                                   const int* __restrict__ idx,
                                                   const float* __restrict__ newxyz,
                                                   const uint16_t* __restrict__ w0b,
                                                   const float* __restrict__ b0,
                                                   uint16_t* __restrict__ z0){
    const int wave = threadIdx.x >> 6, lane = threadIdx.x & 63;
    const int q = lane >> 4, l16 = lane & 15;
    const int r0 = blockIdx.x*64 + wave*16;
    const int row = r0 + l16;
    const int b = row >> 15;
    const int bs = row >> 5;
    const int id = idx[row];
    const float* prow = pts + (((size_t)b << 12) + id)*64;
    const float* xr   = xyz + (((size_t)b << 12) + id)*3;
    const float* qr   = newxyz + (size_t)bs*3;
    float d0 = xr[0]-qr[0], d1 = xr[1]-qr[1], d2 = xr[2]-qr[2];

    bf16x8 Bf[4][3];
#pragma unroll
    for (int nt = 0; nt < 4; ++nt)
#pragma unroll
        for (int s = 0; s < 3; ++s)
            Bf[nt][s] = load_bf8(w0b + (nt*16 + l16)*96 + s*32 + q*8);

    f32x4 acc[4];
#pragma unroll
    for (int nt = 0; nt < 4; ++nt) acc[nt] = (f32x4){0.f,0.f,0.f,0.f};

#pragma unroll
    for (int s = 0; s < 3; ++s){
        const int k0 = s*32 + q*8;
        bf16x8 a;
#pragma unroll
        for (int j = 0; j < 8; ++j){
            int k = k0 + j;
            float v = (k < 3) ? ((k == 0) ? d0 : ((k == 1) ? d1 : d2))
                              : ((k < 67) ? prow[k-3] : 0.f);
            a[j] = (short)f2bf(v);
        }
#pragma unroll
        for (int nt = 0; nt < 4; ++nt)
            acc[nt] = __builtin_amdgcn_mfma_f32_16x16x32_bf16(a, Bf[nt][s], acc[nt], 0, 0, 0);
    }
    // C/D: col=lane&15, row=quad*4+reg (HW-verified layout)
#pragma unroll
    for (int nt = 0; nt < 4; ++nt){
        int c = nt*16 + l16;
        float bb = b0[c];
#pragma unroll
        for (int reg = 0; reg < 4; ++reg){
            int rr = r0 + q*4 + reg;
            z0[(size_t)rr*64 + c] = f2bf(acc[nt][reg] + bb);
        }
    }
}

// ---------------------------------------------------------------- layers 1,2: BN+relu on A, GEMM K=64 (MFMA)
template<int COUT>
__global__ __launch_bounds__(256) void layer_mfma(const uint16_t* __restrict__ zin,
                                                  const float* __restrict__ scale,
                                                  const float* __restrict__ shift,
                                                  const uint16_t* __restrict__ wb,
                                                  const float* __restrict__ bias,
                                                  uint16_t* __restrict__ zout){
    constexpr int NT = COUT/16;
    const int wave = threadIdx.x >> 6, lane = threadIdx.x & 63;
    const int q = lane >> 4, l16 = lane & 15;
    const int r0 = blockIdx.x*64 + wave*16;

    bf16x8 Bf[NT][2];
#pragma unroll
    for (int nt = 0; nt < NT; ++nt)
#pragma unroll
        for (int s = 0; s < 2; ++s)
            Bf[nt][s] = load_bf8(wb + (nt*16 + l16)*64 + s*32 + q*8);

    float sc[2][8], sh[2][8];
#pragma unroll
    for (int s = 0; s < 2; ++s){
        float4 a0 = *reinterpret_cast<const float4*>(scale + s*32 + q*8);
        float4 a1 = *reinterpret_cast<const float4*>(scale + s*32 + q*8 + 4);
        float4 b0_ = *reinterpret_cast<const float4*>(shift + s*32 + q*8);
        float4 b1_ = *reinterpret_cast<const float4*>(shift + s*32 + q*8 + 4);
        sc[s][0]=a0.x; sc[s][1]=a0.y; sc[s][2]=a0.z; sc[s][3]=a0.w;
        sc[s][4]=a1.x; sc[s][5]=a1.y; sc[s][6]=a1.z; sc[s][7]=a1.w;
        sh[s][0]=b0_.x; sh[s][1]=b0_.y; sh[s][2]=b0_.z; sh[s][3]=b0_.w;
        sh[s][4]=b1_.x; sh[s][5]=b1_.y; sh[s][6]=b1_.z; sh[s][7]=b1_.w;
    }

    f32x4 acc[NT];
#pragma unroll
    for (int nt = 0; nt < NT; ++nt) acc[nt] = (f32x4){0.f,0.f,0.f,0.f};

    const uint16_t* zr = zin + (size_t)(r0 + l16)*64;
#pragma unroll
    for (int s = 0; s < 2; ++s){
        uint4 u = *reinterpret_cast<const uint4*>(zr + s*32 + q*8);
        float h[8];
        h[0] = bf2f((uint16_t)(u.x & 0xFFFF)); h[1] = bf2f((uint16_t)(u.x >> 16));
        h[2] = bf2f((uint16_t)(u.y & 0xFFFF)); h[3] = bf2f((uint16_t)(u.y >> 16));
        h[4] = bf2f((uint16_t)(u.z & 0xFFFF)); h[5] = bf2f((uint16_t)(u.z >> 16));
        h[6] = bf2f((uint16_t)(u.w & 0xFFFF)); h[7] = bf2f((uint16_t)(u.w >> 16));
        bf16x8 a;
#pragma unroll
        for (int j = 0; j < 8; ++j){
            float v = fmaxf(fmaf(h[j], sc[s][j], sh[s][j]), 0.f);
            a[j] = (short)f2bf(v);
        }
#pragma unroll
        for (int nt = 0; nt < NT; ++nt)
            acc[nt] = __builtin_amdgcn_mfma_f32_16x16x32_bf16(a, Bf[nt][s], acc[nt], 0, 0, 0);
    }
#pragma unroll
    for (int nt = 0; nt < NT; ++nt){
        int c = nt*16 + l16;
        float bb = bias[c];
#pragma unroll
        for (int reg = 0; reg < 4; ++reg){
            int rr = r0 + q*4 + reg;
            zout[(size_t)rr*COUT + c] = f2bf(acc[nt][reg] + bb);
        }
    }
}

// ---------------------------------------------------------------- per-channel stats (unchanged)
template<int C>
__global__ __launch_bounds__(256) void stats_kernel(const uint16_t* __restrict__ z,
                                                    double* __restrict__ accum){
    constexpr int SH = (C == 64) ? 6 : 7;
    int t = blockIdx.x*256 + threadIdx.x;
    int c = t & (C-1);
    int row0 = t >> SH;
    int stride = (gridDim.x*256) >> SH;
    float s = 0.f, qsum = 0.f;
    for (int r = row0; r < NROWS; r += stride){
        float v = bf2f(z[(size_t)r*C + c]);
        s += v;
        qsum = fmaf(v, v, qsum);
    }
    __shared__ float ss[256], qq[256];
    ss[threadIdx.x] = s; qq[threadIdx.x] = qsum;
    __syncthreads();
    if (threadIdx.x < C){
        for (int u = threadIdx.x + C; u < 256; u += C){ s += ss[u]; qsum += qq[u]; }
        atomicAdd(&accum[c],     (double)s);
        atomicAdd(&accum[C + c], (double)qsum);
    }
}

__global__ void finalize_kernel(const double* __restrict__ accum,
                                const float* __restrict__ g, const float* __restrict__ be,
                                float* __restrict__ scale, float* __restrict__ shift, int C){
    int c = threadIdx.x;
    if (c >= C) return;
    double mean = accum[c] / (double)NROWS;
    double var  = accum[C + c] / (double)NROWS - mean*mean;
    double rs = 1.0 / sqrt(var + 1e-5);
    double sc = (double)g[c] * rs;
    scale[c] = (float)sc;
    shift[c] = (float)((double)be[c] - mean*sc);
}

// ---------------------------------------------------------------- final BN + max-pool + transpose (unchanged)
__global__ __launch_bounds__(256) void final_kernel(const uint16_t* __restrict__ z2,
                                                    const float* __restrict__ scale,
                                                    const float* __restrict__ shift,
                                                    float* __restrict__ out){
    int t = blockIdx.x*256 + threadIdx.x;   // 1048576
    int o = t & 127;
    int s = (t >> 7) & 1023;
    int b = t >> 17;
    const uint16_t* zr = z2 + ((size_t)(((b << 10) | s)) * NK) * 128 + o;
    float vmax = -1e30f, vmin = 1e30f;
#pragma unroll 4
    for (int k = 0; k < NK; ++k){
        float v = bf2f(zr[(size_t)k*128]);
        vmax = fmaxf(vmax, v);
        vmin = fminf(vmin, v);
    }
    float sc = scale[o], sh = shift[o];
    float zsel = (sc >= 0.f) ? vmax : vmin;
    float y = fmaxf(fmaf(zsel, sc, sh), 0.f);
    out[24576 + ((size_t)b << 17) + ((size_t)o << 10) + s] = y;
}

// ---------------------------------------------------------------- launch
extern "C" void kernel_launch(void* const* d_in, const int* in_sizes, int n_in,
                              void* d_out, int out_size, void* d_ws, size_t ws_size,
                              hipStream_t stream) {
    const float* xyz = (const float*)d_in[0];
    const float* pts = (const float*)d_in[1];
    const float* w0  = (const float*)d_in[2];
    const float* b0  = (const float*)d_in[3];
    const float* g0  = (const float*)d_in[4];
    const float* be0 = (const float*)d_in[5];
    const float* w1  = (const float*)d_in[6];
    const float* b1  = (const float*)d_in[7];
    const float* g1  = (const float*)d_in[8];
    const float* be1 = (const float*)d_in[9];
    const float* w2  = (const float*)d_in[10];
    const float* b2  = (const float*)d_in[11];
    const float* g2  = (const float*)d_in[12];
    const float* be2 = (const float*)d_in[13];
    float* out = (float*)d_out;

    char* ws = (char*)d_ws;
    double*   accum  = (double*)(ws + 0);           // 512 doubles
    float*    scale0 = (float*)(ws + 4096);
    float*    shift0 = (float*)(ws + 4352);
    float*    scale1 = (float*)(ws + 4608);
    float*    shift1 = (float*)(ws + 4864);
    float*    scale2 = (float*)(ws + 5120);
    float*    shift2 = (float*)(ws + 5632);
    uint16_t* w0b    = (uint16_t*)(ws + 6144);      // 64*96 bf16
    uint16_t* w1b    = (uint16_t*)(ws + 18432);     // 64*64 bf16
    uint16_t* w2b    = (uint16_t*)(ws + 26624);     // 128*64 bf16
    int*      idx    = (int*)(ws + 43008);          // 262144 ints
    uint16_t* z0     = (uint16_t*)(ws + 1091584);   // 262144*64 bf16
    uint16_t* z1     = (uint16_t*)(ws + 34646016);  // 262144*64 bf16
    uint16_t* z2     = (uint16_t*)(ws + 68200448);  // 262144*128 bf16

    hipMemsetAsync(accum, 0, 4096, stream);

    prep_kernel<<<32, 256, 0, stream>>>(w0, w1, w2, w0b, w1b, w2b);
    fps_kernel<<<NB, 256, 0, stream>>>(xyz, out);
    qball_kernel<<<2048, 256, 0, stream>>>(xyz, out, idx);
    layer0_mfma<<<4096, 256, 0, stream>>>(xyz, pts, idx, out, w0b, b0, z0);
    stats_kernel<64><<<512, 256, 0, stream>>>(z0, accum + 0);
    finalize_kernel<<<1, 64, 0, stream>>>(accum + 0, g0, be0, scale0, shift0, 64);
    layer_mfma<64><<<4096, 256, 0, stream>>>(z0, scale0, shift0, w1b, b1, z1);
    stats_kernel<64><<<512, 256, 0, stream>>>(z1, accum + 128);
    finalize_kernel<<<1, 64, 0, stream>>>(accum + 128, g1, be1, scale1, shift1, 64);
    layer_mfma<128><<<4096, 256, 0, stream>>>(z1, scale1, shift1, w2b, b2, z2);
    stats_kernel<128><<<1024, 256, 0, stream>>>(z2, accum + 256);
    finalize_kernel<<<1, 128, 0, stream>>>(accum + 256, g2, be2, scale2, shift2, 128);
    final_kernel<<<4096, 256, 0, stream>>>(z2, scale2, shift2, out);
}

// Round 6
// 984.277 us; speedup vs baseline: 1.2428x; 1.2428x over previous
//
#include <hip/hip_runtime.h>
#include <stdint.h>

#define NB 8
#define NPTS 4096
#define NS 1024
#define NK 32
#define PC 64        // point feature channels
#define NROWS (NB*NS*NK)   // 262144
#define R2 0.04f

typedef __attribute__((ext_vector_type(8))) short bf16x8;   // 8 bf16 in 4 VGPRs
typedef __attribute__((ext_vector_type(4))) float f32x4;    // MFMA 16x16 accumulator

__device__ __forceinline__ float bf2f(uint16_t u){
    uint32_t v = ((uint32_t)u) << 16;
    return __uint_as_float(v);
}
__device__ __forceinline__ uint16_t f2bf(float f){
    uint32_t u = __float_as_uint(f);
    uint32_t r = (u + 0x7FFFu + ((u >> 16) & 1u)) >> 16;
    return (uint16_t)r;
}
__device__ __forceinline__ bf16x8 load_bf8(const uint16_t* p){
    return *reinterpret_cast<const bf16x8*>(p);
}

// 64-bit max with a DPP-moved partner; masked-off / invalid lanes receive 0,
// which never wins (low word of a real key is ~idx >= 0xFFFFF000 != 0).
#define DPPMAX64(key, ctrl, rmask)                                             \
    {                                                                          \
        uint32_t _lo = (uint32_t)(key), _hi = (uint32_t)((key) >> 32);         \
        uint32_t _olo = (uint32_t)__builtin_amdgcn_update_dpp(                 \
            0, (int)_lo, (ctrl), (rmask), 0xf, true);                          \
        uint32_t _ohi = (uint32_t)__builtin_amdgcn_update_dpp(                 \
            0, (int)_hi, (ctrl), (rmask), 0xf, true);                          \
        unsigned long long _o = (((unsigned long long)_ohi) << 32) | _olo;     \
        key = (_o > (key)) ? _o : (key);                                       \
    }

// ---------------------------------------------------------------- FPS
// Round-4 structure (proven 610 us) with ONE change: centroids buffered in
// LDS (SC) and written to global after the loop. Rationale: __syncthreads
// orders global ops -> compiler emits s_waitcnt vmcnt(0) before s_barrier,
// so the old per-iter t==0 global store put ~500 cyc of HBM store latency
// on every iteration's critical path. LDS store drains via lgkmcnt (cheap).
// DO NOT TOUCH the distance math: plain mul+add with contract(off) is
// bit-exact vs reference (verified rounds 2-5).
// r5 lesson: do NOT move the argmax select out of the distance loop — it
// overlaps with distance issue there; a post-reduce owner-find serializes.
#define FT 16
__global__ __launch_bounds__(256) void fps_kernel(const float* __restrict__ xyz,
                                                  float* __restrict__ out_newxyz){
    __shared__ float LX[NPTS], LY[NPTS], LZ[NPTS];
    __shared__ float4 SC[NS];
    __shared__ unsigned long long cand[2][4];
    const int b = blockIdx.x, t = threadIdx.x;
    const float* base = xyz + (size_t)b * (NPTS*3);
    float px[FT], py[FT], pz[FT], pd[FT];
#pragma unroll
    for (int j = 0; j < FT; ++j){
        int i = t*FT + j;
        float x = base[i*3+0], y = base[i*3+1], z = base[i*3+2];
        px[j]=x; py[j]=y; pz[j]=z; pd[j]=1e10f;
        LX[i]=x; LY[i]=y; LZ[i]=z;
    }
    __syncthreads();
    int cur = 0;
    const int wave = t >> 6, lane = t & 63;
    for (int s = 0; s < NS; ++s){
        float cx = LX[cur], cy = LY[cur], cz = LZ[cur];
        if (t == 0) SC[s] = make_float4(cx, cy, cz, 0.f);
        float bestd = -1.0f; int besti = 0;
#pragma unroll
        for (int j = 0; j < FT; ++j){
            float d;
            {
#pragma clang fp contract(off)
                float dx = px[j]-cx, dy = py[j]-cy, dz = pz[j]-cz;
                d = ((dx*dx) + (dy*dy)) + (dz*dz);
            }
            float nd = fminf(pd[j], d);
            pd[j] = nd;
            if (nd > bestd){ bestd = nd; besti = t*FT + j; }
        }
        unsigned long long key =
            (((unsigned long long)__float_as_uint(bestd)) << 32) |
            (unsigned long long)(~(unsigned)besti);
        DPPMAX64(key, 0x111, 0xf);   // row_shr:1
        DPPMAX64(key, 0x112, 0xf);   // row_shr:2
        DPPMAX64(key, 0x114, 0xf);   // row_shr:4
        DPPMAX64(key, 0x118, 0xf);   // row_shr:8
        DPPMAX64(key, 0x142, 0xa);   // row_bcast:15 -> rows 1,3
        DPPMAX64(key, 0x143, 0xc);   // row_bcast:31 -> rows 2,3
        int p = s & 1;
        if (lane == 63) cand[p][wave] = key;
        __syncthreads();
        unsigned long long k0 = cand[p][0], k1 = cand[p][1];
        unsigned long long k2 = cand[p][2], k3 = cand[p][3];
        unsigned long long m01 = (k0 > k1) ? k0 : k1;
        unsigned long long m23 = (k2 > k3) ? k2 : k3;
        unsigned long long km  = (m01 > m23) ? m01 : m23;
        cur = (int)(~(uint32_t)km);
    }
    __syncthreads();
    for (int i = t; i < NS; i += 256){
        float4 c = SC[i];
        float* o = out_newxyz + ((size_t)b*NS + i)*3;
        o[0] = c.x; o[1] = c.y; o[2] = c.z;
    }
}

// ---------------------------------------------------------------- query ball
// UNCHANGED (verified).
__global__ __launch_bounds__(256) void qball_kernel(const float* __restrict__ xyz,
                                                    const float* __restrict__ newxyz,
                                                    int* __restrict__ idx_out){
    int gid = blockIdx.x*256 + threadIdx.x;
    int w = gid >> 6, lane = gid & 63;
    int b = w >> 10;
    const float* q = newxyz + (size_t)w*3;
    float qx = q[0], qy = q[1], qz = q[2];
    float qn = qx*qx;
    qn = fmaf(qy, qy, qn);
    qn = fmaf(qz, qz, qn);
    const float* base = xyz + (size_t)b * (NPTS*3);
    int cnt = 0, first = 0;
    for (int c0 = 0; c0 < NPTS; c0 += 64){
        int i = c0 + lane;
        float x = base[i*3+0], y = base[i*3+1], z = base[i*3+2];
        float xn = x*x;
        xn = fmaf(y, y, xn);
        xn = fmaf(z, z, xn);
        float dot = qx*x;
        dot = fmaf(qy, y, dot);
        dot = fmaf(qz, z, dot);
        float d;
        {
#pragma clang fp contract(off)
            d = -2.0f * dot;
            d = d + qn;
            d = d + xn;
        }
        bool in = !(d > R2);
        unsigned long long m = __ballot(in);
        if (in){
            int rank = __popcll(m & ((1ull << lane) - 1ull));
            int pos = cnt + rank;
            if (pos < NK) idx_out[(size_t)w*NK + pos] = i;
        }
        if (cnt == 0 && m) first = c0 + (__ffsll((unsigned long long)m) - 1);
        cnt += __popcll(m);
        if (cnt >= NK) break;
    }
    if (cnt < NK){
        for (int p = cnt + lane; p < NK; p += 64) idx_out[(size_t)w*NK + p] = first;
    }
}

// ---------------------------------------------------------------- weight prep (fp32 -> bf16)
// MFMA B-operand wants [out][in] k-contiguous = ORIGINAL layout. w0 padded 67->96.
__global__ void prep_kernel(const float* __restrict__ w0, const float* __restrict__ w1,
                            const float* __restrict__ w2, uint16_t* __restrict__ w0b,
                            uint16_t* __restrict__ w1b, uint16_t* __restrict__ w2b){
    int t = blockIdx.x*256 + threadIdx.x;
    int stride = gridDim.x*256;
    for (int i = t; i < 64*96; i += stride){
        int n = i/96, c = i%96;
        w0b[i] = (c < 67) ? f2bf(w0[n*67 + c]) : (uint16_t)0;
    }
    for (int i = t; i < 64*64; i += stride)  w1b[i] = f2bf(w1[i]);
    for (int i = t; i < 128*64; i += stride) w2b[i] = f2bf(w2[i]);
}

// ---------------------------------------------------------------- layer 0: gather + GEMM 262144 x 96 -> 64 (MFMA)
__global__ __launch_bounds__(256) void layer0_mfma(const float* __restrict__ xyz,
                                                   const float* __restrict__ pts,
                                                   const int* __restrict__ idx,
                                                   const float* __restrict__ newxyz,
                                                   const uint16_t* __restrict__ w0b,
                                                   const float* __restrict__ b0,
                                                   uint16_t* __restrict__ z0){
    const int wave = threadIdx.x >> 6, lane = threadIdx.x & 63;
    const int q = lane >> 4, l16 = lane & 15;
    const int r0 = blockIdx.x*64 + wave*16;
    const int row = r0 + l16;
    const int b = row >> 15;
    const int bs = row >> 5;
    const int id = idx[row];
    const float* prow = pts + (((size_t)b << 12) + id)*64;
    const float* xr   = xyz + (((size_t)b << 12) + id)*3;
    const float* qr   = newxyz + (size_t)bs*3;
    float d0 = xr[0]-qr[0], d1 = xr[1]-qr[1], d2 = xr[2]-qr[2];

    bf16x8 Bf[4][3];
#pragma unroll
    for (int nt = 0; nt < 4; ++nt)
#pragma unroll
        for (int s = 0; s < 3; ++s)
            Bf[nt][s] = load_bf8(w0b + (nt*16 + l16)*96 + s*32 + q*8);

    f32x4 acc[4];
#pragma unroll
    for (int nt = 0; nt < 4; ++nt) acc[nt] = (f32x4){0.f,0.f,0.f,0.f};

#pragma unroll
    for (int s = 0; s < 3; ++s){
        const int k0 = s*32 + q*8;
        bf16x8 a;
#pragma unroll
        for (int j = 0; j < 8; ++j){
            int k = k0 + j;
            float v = (k < 3) ? ((k == 0) ? d0 : ((k == 1) ? d1 : d2))
                              : ((k < 67) ? prow[k-3] : 0.f);
            a[j] = (short)f2bf(v);
        }
#pragma unroll
        for (int nt = 0; nt < 4; ++nt)
            acc[nt] = __builtin_amdgcn_mfma_f32_16x16x32_bf16(a, Bf[nt][s], acc[nt], 0, 0, 0);
    }
    // C/D: col=lane&15, row=quad*4+reg (HW-verified layout)
#pragma unroll
    for (int nt = 0; nt < 4; ++nt){
        int c = nt*16 + l16;
        float bb = b0[c];
#pragma unroll
        for (int reg = 0; reg < 4; ++reg){
            int rr = r0 + q*4 + reg;
            z0[(size_t)rr*64 + c] = f2bf(acc[nt][reg] + bb);
        }
    }
}

// ---------------------------------------------------------------- layers 1,2: BN+relu on A, GEMM K=64 (MFMA)
template<int COUT>
__global__ __launch_bounds__(256) void layer_mfma(const uint16_t* __restrict__ zin,
                                                  const float* __restrict__ scale,
                                                  const float* __restrict__ shift,
                                                  const uint16_t* __restrict__ wb,
                                                  const float* __restrict__ bias,
                                                  uint16_t* __restrict__ zout){
    constexpr int NT = COUT/16;
    const int wave = threadIdx.x >> 6, lane = threadIdx.x & 63;
    const int q = lane >> 4, l16 = lane & 15;
    const int r0 = blockIdx.x*64 + wave*16;

    bf16x8 Bf[NT][2];
#pragma unroll
    for (int nt = 0; nt < NT; ++nt)
#pragma unroll
        for (int s = 0; s < 2; ++s)
            Bf[nt][s] = load_bf8(wb + (nt*16 + l16)*64 + s*32 + q*8);

    float sc[2][8], sh[2][8];
#pragma unroll
    for (int s = 0; s < 2; ++s){
        float4 a0 = *reinterpret_cast<const float4*>(scale + s*32 + q*8);
        float4 a1 = *reinterpret_cast<const float4*>(scale + s*32 + q*8 + 4);
        float4 b0_ = *reinterpret_cast<const float4*>(shift + s*32 + q*8);
        float4 b1_ = *reinterpret_cast<const float4*>(shift + s*32 + q*8 + 4);
        sc[s][0]=a0.x; sc[s][1]=a0.y; sc[s][2]=a0.z; sc[s][3]=a0.w;
        sc[s][4]=a1.x; sc[s][5]=a1.y; sc[s][6]=a1.z; sc[s][7]=a1.w;
        sh[s][0]=b0_.x; sh[s][1]=b0_.y; sh[s][2]=b0_.z; sh[s][3]=b0_.w;
        sh[s][4]=b1_.x; sh[s][5]=b1_.y; sh[s][6]=b1_.z; sh[s][7]=b1_.w;
    }

    f32x4 acc[NT];
#pragma unroll
    for (int nt = 0; nt < NT; ++nt) acc[nt] = (f32x4){0.f,0.f,0.f,0.f};

    const uint16_t* zr = zin + (size_t)(r0 + l16)*64;
#pragma unroll
    for (int s = 0; s < 2; ++s){
        uint4 u = *reinterpret_cast<const uint4*>(zr + s*32 + q*8);
        float h[8];
        h[0] = bf2f((uint16_t)(u.x & 0xFFFF)); h[1] = bf2f((uint16_t)(u.x >> 16));
        h[2] = bf2f((uint16_t)(u.y & 0xFFFF)); h[3] = bf2f((uint16_t)(u.y >> 16));
        h[4] = bf2f((uint16_t)(u.z & 0xFFFF)); h[5] = bf2f((uint16_t)(u.z >> 16));
        h[6] = bf2f((uint16_t)(u.w & 0xFFFF)); h[7] = bf2f((uint16_t)(u.w >> 16));
        bf16x8 a;
#pragma unroll
        for (int j = 0; j < 8; ++j){
            float v = fmaxf(fmaf(h[j], sc[s][j], sh[s][j]), 0.f);
            a[j] = (short)f2bf(v);
        }
#pragma unroll
        for (int nt = 0; nt < NT; ++nt)
            acc[nt] = __builtin_amdgcn_mfma_f32_16x16x32_bf16(a, Bf[nt][s], acc[nt], 0, 0, 0);
    }
#pragma unroll
    for (int nt = 0; nt < NT; ++nt){
        int c = nt*16 + l16;
        float bb = bias[c];
#pragma unroll
        for (int reg = 0; reg < 4; ++reg){
            int rr = r0 + q*4 + reg;
            zout[(size_t)rr*COUT + c] = f2bf(acc[nt][reg] + bb);
        }
    }
}

// ---------------------------------------------------------------- per-channel stats (unchanged)
template<int C>
__global__ __launch_bounds__(256) void stats_kernel(const uint16_t* __restrict__ z,
                                                    double* __restrict__ accum){
    constexpr int SH = (C == 64) ? 6 : 7;
    int t = blockIdx.x*256 + threadIdx.x;
    int c = t & (C-1);
    int row0 = t >> SH;
    int stride = (gridDim.x*256) >> SH;
    float s = 0.f, qsum = 0.f;
    for (int r = row0; r < NROWS; r += stride){
        float v = bf2f(z[(size_t)r*C + c]);
        s += v;
        qsum = fmaf(v, v, qsum);
    }
    __shared__ float ss[256], qq[256];
    ss[threadIdx.x] = s; qq[threadIdx.x] = qsum;
    __syncthreads();
    if (threadIdx.x < C){
        for (int u = threadIdx.x + C; u < 256; u += C){ s += ss[u]; qsum += qq[u]; }
        atomicAdd(&accum[c],     (double)s);
        atomicAdd(&accum[C + c], (double)qsum);
    }
}

__global__ void finalize_kernel(const double* __restrict__ accum,
                                const float* __restrict__ g, const float* __restrict__ be,
                                float* __restrict__ scale, float* __restrict__ shift, int C){
    int c = threadIdx.x;
    if (c >= C) return;
    double mean = accum[c] / (double)NROWS;
    double var  = accum[C + c] / (double)NROWS - mean*mean;
    double rs = 1.0 / sqrt(var + 1e-5);
    double sc = (double)g[c] * rs;
    scale[c] = (float)sc;
    shift[c] = (float)((double)be[c] - mean*sc);
}

// ---------------------------------------------------------------- final BN + max-pool + transpose (unchanged)
__global__ __launch_bounds__(256) void final_kernel(const uint16_t* __restrict__ z2,
                                                    const float* __restrict__ scale,
                                                    const float* __restrict__ shift,
                                                    float* __restrict__ out){
    int t = blockIdx.x*256 + threadIdx.x;   // 1048576
    int o = t & 127;
    int s = (t >> 7) & 1023;
    int b = t >> 17;
    const uint16_t* zr = z2 + ((size_t)(((b << 10) | s)) * NK) * 128 + o;
    float vmax = -1e30f, vmin = 1e30f;
#pragma unroll 4
    for (int k = 0; k < NK; ++k){
        float v = bf2f(zr[(size_t)k*128]);
        vmax = fmaxf(vmax, v);
        vmin = fminf(vmin, v);
    }
    float sc = scale[o], sh = shift[o];
    float zsel = (sc >= 0.f) ? vmax : vmin;
    float y = fmaxf(fmaf(zsel, sc, sh), 0.f);
    out[24576 + ((size_t)b << 17) + ((size_t)o << 10) + s] = y;
}

// ---------------------------------------------------------------- launch
extern "C" void kernel_launch(void* const* d_in, const int* in_sizes, int n_in,
                              void* d_out, int out_size, void* d_ws, size_t ws_size,
                              hipStream_t stream) {
    const float* xyz = (const float*)d_in[0];
    const float* pts = (const float*)d_in[1];
    const float* w0  = (const float*)d_in[2];
    const float* b0  = (const float*)d_in[3];
    const float* g0  = (const float*)d_in[4];
    const float* be0 = (const float*)d_in[5];
    const float* w1  = (const float*)d_in[6];
    const float* b1  = (const float*)d_in[7];
    const float* g1  = (const float*)d_in[8];
    const float* be1 = (const float*)d_in[9];
    const float* w2  = (const float*)d_in[10];
    const float* b2  = (const float*)d_in[11];
    const float* g2  = (const float*)d_in[12];
    const float* be2 = (const float*)d_in[13];
    float* out = (float*)d_out;

    char* ws = (char*)d_ws;
    double*   accum  = (double*)(ws + 0);           // 512 doubles
    float*    scale0 = (float*)(ws + 4096);
    float*    shift0 = (float*)(ws + 4352);
    float*    scale1 = (float*)(ws + 4608);
    float*    shift1 = (float*)(ws + 4864);
    float*    scale2 = (float*)(ws + 5120);
    float*    shift2 = (float*)(ws + 5632);
    uint16_t* w0b    = (uint16_t*)(ws + 6144);      // 64*96 bf16
    uint16_t* w1b    = (uint16_t*)(ws + 18432);     // 64*64 bf16
    uint16_t* w2b    = (uint16_t*)(ws + 26624);     // 128*64 bf16
    int*      idx    = (int*)(ws + 43008);          // 262144 ints
    uint16_t* z0     = (uint16_t*)(ws + 1091584);   // 262144*64 bf16
    uint16_t* z1     = (uint16_t*)(ws + 34646016);  // 262144*64 bf16
    uint16_t* z2     = (uint16_t*)(ws + 68200448);  // 262144*128 bf16

    hipMemsetAsync(accum, 0, 4096, stream);

    prep_kernel<<<32, 256, 0, stream>>>(w0, w1, w2, w0b, w1b, w2b);
    fps_kernel<<<NB, 256, 0, stream>>>(xyz, out);
    qball_kernel<<<2048, 256, 0, stream>>>(xyz, out, idx);
    layer0_mfma<<<4096, 256, 0, stream>>>(xyz, pts, idx, out, w0b, b0, z0);
    stats_kernel<64><<<512, 256, 0, stream>>>(z0, accum + 0);
    finalize_kernel<<<1, 64, 0, stream>>>(accum + 0, g0, be0, scale0, shift0, 64);
    layer_mfma<64><<<4096, 256, 0, stream>>>(z0, scale0, shift0, w1b, b1, z1);
    stats_kernel<64><<<512, 256, 0, stream>>>(z1, accum + 128);
    finalize_kernel<<<1, 64, 0, stream>>>(accum + 128, g1, be1, scale1, shift1, 64);
    layer_mfma<128><<<4096, 256, 0, stream>>>(z1, scale1, shift1, w2b, b2, z2);
    stats_kernel<128><<<1024, 256, 0, stream>>>(z2, accum + 256);
    finalize_kernel<<<1, 128, 0, stream>>>(accum + 256, g2, be2, scale2, shift2, 128);
    final_kernel<<<4096, 256, 0, stream>>>(z2, scale2, shift2, out);
}

// Round 7
// 848.904 us; speedup vs baseline: 1.4410x; 1.1595x over previous
//
#include <hip/hip_runtime.h>
#include <stdint.h>

#define NB 8
#define NPTS 4096
#define NS 1024
#define NK 32
#define NROWS (NB*NS*NK)   // 262144
#define R2 0.04f
#define NCOPY 8            // atomic spreading copies for stats accum

typedef __attribute__((ext_vector_type(8))) short bf16x8;   // 8 bf16 in 4 VGPRs
typedef __attribute__((ext_vector_type(4))) float f32x4;    // MFMA 16x16 accumulator

__device__ __forceinline__ float bf2f(uint16_t u){
    uint32_t v = ((uint32_t)u) << 16;
    return __uint_as_float(v);
}
__device__ __forceinline__ uint16_t f2bf(float f){
    uint32_t u = __float_as_uint(f);
    uint32_t r = (u + 0x7FFFu + ((u >> 16) & 1u)) >> 16;
    return (uint16_t)r;
}
__device__ __forceinline__ bf16x8 load_bf8(const uint16_t* p){
    return *reinterpret_cast<const bf16x8*>(p);
}

// 64-bit max with a DPP-moved partner; masked-off / invalid lanes receive 0,
// which never wins (low word of a real key is ~idx >= 0xFFFFF000 != 0).
#define DPPMAX64(key, ctrl, rmask)                                             \
    {                                                                          \
        uint32_t _lo = (uint32_t)(key), _hi = (uint32_t)((key) >> 32);         \
        uint32_t _olo = (uint32_t)__builtin_amdgcn_update_dpp(                 \
            0, (int)_lo, (ctrl), (rmask), 0xf, true);                          \
        uint32_t _ohi = (uint32_t)__builtin_amdgcn_update_dpp(                 \
            0, (int)_hi, (ctrl), (rmask), 0xf, true);                          \
        unsigned long long _o = (((unsigned long long)_ohi) << 32) | _olo;     \
        key = (_o > (key)) ? _o : (key);                                       \
    }

// ---------------------------------------------------------------- FPS
// r4/r6 structure — measured 607 us, near its issue+tail floor. UNCHANGED.
// DO NOT TOUCH the distance math (bit-exact vs reference, rounds 2-6).
#define FT 16
__global__ __launch_bounds__(256) void fps_kernel(const float* __restrict__ xyz,
                                                  float* __restrict__ out_newxyz){
    __shared__ float LX[NPTS], LY[NPTS], LZ[NPTS];
    __shared__ float4 SC[NS];
    __shared__ unsigned long long cand[2][4];
    const int b = blockIdx.x, t = threadIdx.x;
    const float* base = xyz + (size_t)b * (NPTS*3);
    float px[FT], py[FT], pz[FT], pd[FT];
#pragma unroll
    for (int j = 0; j < FT; ++j){
        int i = t*FT + j;
        float x = base[i*3+0], y = base[i*3+1], z = base[i*3+2];
        px[j]=x; py[j]=y; pz[j]=z; pd[j]=1e10f;
        LX[i]=x; LY[i]=y; LZ[i]=z;
    }
    __syncthreads();
    int cur = 0;
    const int wave = t >> 6, lane = t & 63;
    for (int s = 0; s < NS; ++s){
        float cx = LX[cur], cy = LY[cur], cz = LZ[cur];
        if (t == 0) SC[s] = make_float4(cx, cy, cz, 0.f);
        float bestd = -1.0f; int besti = 0;
#pragma unroll
        for (int j = 0; j < FT; ++j){
            float d;
            {
#pragma clang fp contract(off)
                float dx = px[j]-cx, dy = py[j]-cy, dz = pz[j]-cz;
                d = ((dx*dx) + (dy*dy)) + (dz*dz);
            }
            float nd = fminf(pd[j], d);
            pd[j] = nd;
            if (nd > bestd){ bestd = nd; besti = t*FT + j; }
        }
        unsigned long long key =
            (((unsigned long long)__float_as_uint(bestd)) << 32) |
            (unsigned long long)(~(unsigned)besti);
        DPPMAX64(key, 0x111, 0xf);   // row_shr:1
        DPPMAX64(key, 0x112, 0xf);   // row_shr:2
        DPPMAX64(key, 0x114, 0xf);   // row_shr:4
        DPPMAX64(key, 0x118, 0xf);   // row_shr:8
        DPPMAX64(key, 0x142, 0xa);   // row_bcast:15 -> rows 1,3
        DPPMAX64(key, 0x143, 0xc);   // row_bcast:31 -> rows 2,3
        int p = s & 1;
        if (lane == 63) cand[p][wave] = key;
        __syncthreads();
        unsigned long long k0 = cand[p][0], k1 = cand[p][1];
        unsigned long long k2 = cand[p][2], k3 = cand[p][3];
        unsigned long long m01 = (k0 > k1) ? k0 : k1;
        unsigned long long m23 = (k2 > k3) ? k2 : k3;
        unsigned long long km  = (m01 > m23) ? m01 : m23;
        cur = (int)(~(uint32_t)km);
    }
    __syncthreads();
    for (int i = t; i < NS; i += 256){
        float4 c = SC[i];
        float* o = out_newxyz + ((size_t)b*NS + i)*3;
        o[0] = c.x; o[1] = c.y; o[2] = c.z;
    }
}

// ---------------------------------------------------------------- query ball
// UNCHANGED (verified).
__global__ __launch_bounds__(256) void qball_kernel(const float* __restrict__ xyz,
                                                    const float* __restrict__ newxyz,
                                                    int* __restrict__ idx_out){
    int gid = blockIdx.x*256 + threadIdx.x;
    int w = gid >> 6, lane = gid & 63;
    int b = w >> 10;
    const float* q = newxyz + (size_t)w*3;
    float qx = q[0], qy = q[1], qz = q[2];
    float qn = qx*qx;
    qn = fmaf(qy, qy, qn);
    qn = fmaf(qz, qz, qn);
    const float* base = xyz + (size_t)b * (NPTS*3);
    int cnt = 0, first = 0;
    for (int c0 = 0; c0 < NPTS; c0 += 64){
        int i = c0 + lane;
        float x = base[i*3+0], y = base[i*3+1], z = base[i*3+2];
        float xn = x*x;
        xn = fmaf(y, y, xn);
        xn = fmaf(z, z, xn);
        float dot = qx*x;
        dot = fmaf(qy, y, dot);
        dot = fmaf(qz, z, dot);
        float d;
        {
#pragma clang fp contract(off)
            d = -2.0f * dot;
            d = d + qn;
            d = d + xn;
        }
        bool in = !(d > R2);
        unsigned long long m = __ballot(in);
        if (in){
            int rank = __popcll(m & ((1ull << lane) - 1ull));
            int pos = cnt + rank;
            if (pos < NK) idx_out[(size_t)w*NK + pos] = i;
        }
        if (cnt == 0 && m) first = c0 + (__ffsll((unsigned long long)m) - 1);
        cnt += __popcll(m);
        if (cnt >= NK) break;
    }
    if (cnt < NK){
        for (int p = cnt + lane; p < NK; p += 64) idx_out[(size_t)w*NK + p] = first;
    }
}

// ---------------------------------------------------------------- weight prep (fp32 -> bf16)
__global__ void prep_kernel(const float* __restrict__ w0, const float* __restrict__ w1,
                            const float* __restrict__ w2, uint16_t* __restrict__ w0b,
                            uint16_t* __restrict__ w1b, uint16_t* __restrict__ w2b){
    int t = blockIdx.x*256 + threadIdx.x;
    int stride = gridDim.x*256;
    for (int i = t; i < 64*96; i += stride){
        int n = i/96, c = i%96;
        w0b[i] = (c < 67) ? f2bf(w0[n*67 + c]) : (uint16_t)0;
    }
    for (int i = t; i < 64*64; i += stride)  w1b[i] = f2bf(w1[i]);
    for (int i = t; i < 128*64; i += stride) w2b[i] = f2bf(w2[i]);
}

// ---------------------------------------------------------------- layer 0: gather + GEMM 262144 x 96 -> 64 (MFMA) + fused stats
__global__ __launch_bounds__(256) void layer0_mfma(const float* __restrict__ xyz,
                                                   const float* __restrict__ pts,
                                                   const int* __restrict__ idx,
                                                   const float* __restrict__ newxyz,
                                                   const uint16_t* __restrict__ w0b,
                                                   const float* __restrict__ b0,
                                                   uint16_t* __restrict__ z0,
                                                   double* __restrict__ accumOut){
    __shared__ float S_s[16][64], S_q[16][64];
    const int wave = threadIdx.x >> 6, lane = threadIdx.x & 63;
    const int q = lane >> 4, l16 = lane & 15;
    const int r0 = blockIdx.x*64 + wave*16;
    const int row = r0 + l16;
    const int b = row >> 15;
    const int bs = row >> 5;
    const int id = idx[row];
    const float* prow = pts + (((size_t)b << 12) + id)*64;
    const float* xr   = xyz + (((size_t)b << 12) + id)*3;
    const float* qr   = newxyz + (size_t)bs*3;
    float d0 = xr[0]-qr[0], d1 = xr[1]-qr[1], d2 = xr[2]-qr[2];

    bf16x8 Bf[4][3];
#pragma unroll
    for (int nt = 0; nt < 4; ++nt)
#pragma unroll
        for (int s = 0; s < 3; ++s)
            Bf[nt][s] = load_bf8(w0b + (nt*16 + l16)*96 + s*32 + q*8);

    f32x4 acc[4];
#pragma unroll
    for (int nt = 0; nt < 4; ++nt) acc[nt] = (f32x4){0.f,0.f,0.f,0.f};

#pragma unroll
    for (int s = 0; s < 3; ++s){
        const int k0 = s*32 + q*8;
        bf16x8 a;
#pragma unroll
        for (int j = 0; j < 8; ++j){
            int k = k0 + j;
            float v = (k < 3) ? ((k == 0) ? d0 : ((k == 1) ? d1 : d2))
                              : ((k < 67) ? prow[k-3] : 0.f);
            a[j] = (short)f2bf(v);
        }
#pragma unroll
        for (int nt = 0; nt < 4; ++nt)
            acc[nt] = __builtin_amdgcn_mfma_f32_16x16x32_bf16(a, Bf[nt][s], acc[nt], 0, 0, 0);
    }
    // C/D: col=lane&15, row=quad*4+reg. Epilogue: bias, store, f32 stats partials.
#pragma unroll
    for (int nt = 0; nt < 4; ++nt){
        int c = nt*16 + l16;
        float bb = b0[c];
        float sps = 0.f, spq = 0.f;
#pragma unroll
        for (int reg = 0; reg < 4; ++reg){
            int rr = r0 + q*4 + reg;
            float h = acc[nt][reg] + bb;
            sps += h;
            spq = fmaf(h, h, spq);
            z0[(size_t)rr*64 + c] = f2bf(h);
        }
        S_s[wave*4 + q][c] = sps;
        S_q[wave*4 + q][c] = spq;
    }
    __syncthreads();
    int t = threadIdx.x;
    if (t < 64){
        double ss = 0.0, sq = 0.0;
#pragma unroll
        for (int i = 0; i < 16; ++i){ ss += (double)S_s[i][t]; sq += (double)S_q[i][t]; }
        int cp = blockIdx.x & (NCOPY-1);
        atomicAdd(&accumOut[cp*256 + t], ss);
        atomicAdd(&accumOut[cp*256 + 128 + t], sq);
    }
}

// ---------------------------------------------------------------- layers 1,2: inline BN-param calc + BN+relu+GEMM + fused stats
template<int COUT>
__global__ __launch_bounds__(256) void layer_mfma(const uint16_t* __restrict__ zin,
                                                  const double* __restrict__ accumIn,
                                                  const float* __restrict__ g,
                                                  const float* __restrict__ be,
                                                  const uint16_t* __restrict__ wb,
                                                  const float* __restrict__ bias,
                                                  uint16_t* __restrict__ zout,
                                                  double* __restrict__ accumOut){
    constexpr int NT = COUT/16;
    __shared__ float sc_l[64], sh_l[64];
    __shared__ float S_s[16][COUT], S_q[16][COUT];
    const int t = threadIdx.x;
    if (t < 64){
        double s = 0.0, qq = 0.0;
#pragma unroll
        for (int cp = 0; cp < NCOPY; ++cp){
            s  += accumIn[cp*256 + t];
            qq += accumIn[cp*256 + 128 + t];
        }
        double mean = s / (double)NROWS;
        double var  = qq / (double)NROWS - mean*mean;
        double rs = 1.0 / sqrt(var + 1e-5);
        double scv = (double)g[t] * rs;
        sc_l[t] = (float)scv;
        sh_l[t] = (float)((double)be[t] - mean*scv);
    }
    __syncthreads();

    const int wave = t >> 6, lane = t & 63;
    const int q = lane >> 4, l16 = lane & 15;
    const int r0 = blockIdx.x*64 + wave*16;

    bf16x8 Bf[NT][2];
#pragma unroll
    for (int nt = 0; nt < NT; ++nt)
#pragma unroll
        for (int s = 0; s < 2; ++s)
            Bf[nt][s] = load_bf8(wb + (nt*16 + l16)*64 + s*32 + q*8);

    float sc[2][8], sh[2][8];
#pragma unroll
    for (int s = 0; s < 2; ++s){
        float4 a0 = *reinterpret_cast<const float4*>(&sc_l[s*32 + q*8]);
        float4 a1 = *reinterpret_cast<const float4*>(&sc_l[s*32 + q*8 + 4]);
        float4 b0_ = *reinterpret_cast<const float4*>(&sh_l[s*32 + q*8]);
        float4 b1_ = *reinterpret_cast<const float4*>(&sh_l[s*32 + q*8 + 4]);
        sc[s][0]=a0.x; sc[s][1]=a0.y; sc[s][2]=a0.z; sc[s][3]=a0.w;
        sc[s][4]=a1.x; sc[s][5]=a1.y; sc[s][6]=a1.z; sc[s][7]=a1.w;
        sh[s][0]=b0_.x; sh[s][1]=b0_.y; sh[s][2]=b0_.z; sh[s][3]=b0_.w;
        sh[s][4]=b1_.x; sh[s][5]=b1_.y; sh[s][6]=b1_.z; sh[s][7]=b1_.w;
    }

    f32x4 acc[NT];
#pragma unroll
    for (int nt = 0; nt < NT; ++nt) acc[nt] = (f32x4){0.f,0.f,0.f,0.f};

    const uint16_t* zr = zin + (size_t)(r0 + l16)*64;
#pragma unroll
    for (int s = 0; s < 2; ++s){
        uint4 u = *reinterpret_cast<const uint4*>(zr + s*32 + q*8);
        float h[8];
        h[0] = bf2f((uint16_t)(u.x & 0xFFFF)); h[1] = bf2f((uint16_t)(u.x >> 16));
        h[2] = bf2f((uint16_t)(u.y & 0xFFFF)); h[3] = bf2f((uint16_t)(u.y >> 16));
        h[4] = bf2f((uint16_t)(u.z & 0xFFFF)); h[5] = bf2f((uint16_t)(u.z >> 16));
        h[6] = bf2f((uint16_t)(u.w & 0xFFFF)); h[7] = bf2f((uint16_t)(u.w >> 16));
        bf16x8 a;
#pragma unroll
        for (int j = 0; j < 8; ++j){
            float v = fmaxf(fmaf(h[j], sc[s][j], sh[s][j]), 0.f);
            a[j] = (short)f2bf(v);
        }
#pragma unroll
        for (int nt = 0; nt < NT; ++nt)
            acc[nt] = __builtin_amdgcn_mfma_f32_16x16x32_bf16(a, Bf[nt][s], acc[nt], 0, 0, 0);
    }
#pragma unroll
    for (int nt = 0; nt < NT; ++nt){
        int c = nt*16 + l16;
        float bb = bias[c];
        float sps = 0.f, spq = 0.f;
#pragma unroll
        for (int reg = 0; reg < 4; ++reg){
            int rr = r0 + q*4 + reg;
            float h = acc[nt][reg] + bb;
            sps += h;
            spq = fmaf(h, h, spq);
            zout[(size_t)rr*COUT + c] = f2bf(h);
        }
        S_s[wave*4 + q][c] = sps;
        S_q[wave*4 + q][c] = spq;
    }
    __syncthreads();
    if (t < COUT){
        double ss = 0.0, sq = 0.0;
#pragma unroll
        for (int i = 0; i < 16; ++i){ ss += (double)S_s[i][t]; sq += (double)S_q[i][t]; }
        int cp = blockIdx.x & (NCOPY-1);
        atomicAdd(&accumOut[cp*256 + t], ss);
        atomicAdd(&accumOut[cp*256 + 128 + t], sq);
    }
}

// ---------------------------------------------------------------- final: inline BN-param + BN + max-pool + transpose
__global__ __launch_bounds__(256) void final_kernel(const uint16_t* __restrict__ z2,
                                                    const double* __restrict__ accumIn,
                                                    const float* __restrict__ g,
                                                    const float* __restrict__ be,
                                                    float* __restrict__ out){
    __shared__ float sc_l[128], sh_l[128];
    const int t0 = threadIdx.x;
    if (t0 < 128){
        double s = 0.0, qq = 0.0;
#pragma unroll
        for (int cp = 0; cp < NCOPY; ++cp){
            s  += accumIn[cp*256 + t0];
            qq += accumIn[cp*256 + 128 + t0];
        }
        double mean = s / (double)NROWS;
        double var  = qq / (double)NROWS - mean*mean;
        double rs = 1.0 / sqrt(var + 1e-5);
        double scv = (double)g[t0] * rs;
        sc_l[t0] = (float)scv;
        sh_l[t0] = (float)((double)be[t0] - mean*scv);
    }
    __syncthreads();

    int t = blockIdx.x*256 + threadIdx.x;   // 1048576
    int o = t & 127;
    int s = (t >> 7) & 1023;
    int b = t >> 17;
    const uint16_t* zr = z2 + ((size_t)(((b << 10) | s)) * NK) * 128 + o;
    float vmax = -1e30f, vmin = 1e30f;
#pragma unroll 4
    for (int k = 0; k < NK; ++k){
        float v = bf2f(zr[(size_t)k*128]);
        vmax = fmaxf(vmax, v);
        vmin = fminf(vmin, v);
    }
    float sc = sc_l[o], sh = sh_l[o];
    float zsel = (sc >= 0.f) ? vmax : vmin;
    float y = fmaxf(fmaf(zsel, sc, sh), 0.f);
    out[24576 + ((size_t)b << 17) + ((size_t)o << 10) + s] = y;
}

// ---------------------------------------------------------------- launch
extern "C" void kernel_launch(void* const* d_in, const int* in_sizes, int n_in,
                              void* d_out, int out_size, void* d_ws, size_t ws_size,
                              hipStream_t stream) {
    const float* xyz = (const float*)d_in[0];
    const float* pts = (const float*)d_in[1];
    const float* w0  = (const float*)d_in[2];
    const float* b0  = (const float*)d_in[3];
    const float* g0  = (const float*)d_in[4];
    const float* be0 = (const float*)d_in[5];
    const float* w1  = (const float*)d_in[6];
    const float* b1  = (const float*)d_in[7];
    const float* g1  = (const float*)d_in[8];
    const float* be1 = (const float*)d_in[9];
    const float* w2  = (const float*)d_in[10];
    const float* b2  = (const float*)d_in[11];
    const float* g2  = (const float*)d_in[12];
    const float* be2 = (const float*)d_in[13];
    float* out = (float*)d_out;

    char* ws = (char*)d_ws;
    // accum: 3 layers x NCOPY x 256 doubles = 49152 B
    double*   accum0 = (double*)(ws + 0);
    double*   accum1 = (double*)(ws + 16384);
    double*   accum2 = (double*)(ws + 32768);
    uint16_t* w0b    = (uint16_t*)(ws + 49152);     // 64*96 bf16 (12288)
    uint16_t* w1b    = (uint16_t*)(ws + 61440);     // 64*64 bf16 (8192)
    uint16_t* w2b    = (uint16_t*)(ws + 69632);     // 128*64 bf16 (16384)
    uint16_t* z0     = (uint16_t*)(ws + 86016);     // 33554432 B
    uint16_t* z1     = (uint16_t*)(ws + 33640448);  // 33554432 B
    uint16_t* z2     = (uint16_t*)(ws + 67194880);  // 67108864 B -> ends 134303744
    // idx aliases head of z2 region: dead after layer0, z2 written only in layer2
    int*      idx    = (int*)(ws + 67194880);       // 1 MB

    hipMemsetAsync(ws, 0, 49152, stream);           // zero all accum copies

    prep_kernel<<<32, 256, 0, stream>>>(w0, w1, w2, w0b, w1b, w2b);
    fps_kernel<<<NB, 256, 0, stream>>>(xyz, out);
    qball_kernel<<<2048, 256, 0, stream>>>(xyz, out, idx);
    layer0_mfma<<<4096, 256, 0, stream>>>(xyz, pts, idx, out, w0b, b0, z0, accum0);
    layer_mfma<64><<<4096, 256, 0, stream>>>(z0, accum0, g0, be0, w1b, b1, z1, accum1);
    layer_mfma<128><<<4096, 256, 0, stream>>>(z1, accum1, g1, be1, w2b, b2, z2, accum2);
    final_kernel<<<4096, 256, 0, stream>>>(z2, accum2, g2, be2, out);
}